// Round 1
// baseline (2359.262 us; speedup 1.0000x reference)
//
#include <hip/hip_runtime.h>
#include <hip/hip_bf16.h>

#define E_EDGES 1200000
#define N_NODES 100000
#define TILE_M 96
#define NTILES (E_EDGES / TILE_M)   // 12500, exact
#define KD 192
#define LDP 208   // padded LDS row stride in bf16 elems

typedef float f32x4 __attribute__((ext_vector_type(4)));
typedef __bf16 bf16x8 __attribute__((ext_vector_type(8)));
typedef unsigned short u16x8 __attribute__((ext_vector_type(8)));
typedef unsigned int u32x4 __attribute__((ext_vector_type(4)));
typedef unsigned int u32x2 __attribute__((ext_vector_type(2)));

__device__ inline unsigned short f2bf_u(float f) {
    unsigned int u = __builtin_bit_cast(unsigned int, f);
    return (unsigned short)((u + 0x7fffu + ((u >> 16) & 1u)) >> 16);
}
__device__ inline float splus(float v) {
    return fmaxf(v, 0.f) + __logf(1.f + __expf(-fabsf(v)));
}
__device__ inline float sigm(float v) { return 1.f / (1.f + __expf(-v)); }

// ws (float) layout: [0:192) sum, [192:384) sumsq, [384:576) scale, [576:768) shift,
// [768:832) sum4, [832:896) sq4, [896:960) scale4, [960:1024) shift4
template<int PHASE>
__global__ __launch_bounds__(256, 2)
void gemm_k(const float* __restrict__ x, const int* __restrict__ eidx,
            const float* __restrict__ ea,
            const float* __restrict__ Wc, const float* __restrict__ Wf,
            const float* __restrict__ Wb,
            float* __restrict__ stats, float* __restrict__ outp)
{
    __shared__ unsigned short zl[TILE_M * LDP];   // 39936 B
    float* gl = (float*)zl;                       // phase-2 reuse: gated [96][66]

    const int t = threadIdx.x;
    const int lane = t & 63;
    const int w = t >> 6;          // wave 0..3
    const int l15 = lane & 15;
    const int l4 = lane >> 4;      // 0..3

    // ---- preload B fragments (W is tiny, L2-resident; once per block)
    const float* Wp0 = Wc; const float* Wp1 = Wf; const float* Wp2 = Wb;
    bf16x8 Bf[3][6];
    #pragma unroll
    for (int L = 0; L < 3; ++L) {
        const float* Wrow = (L == 0 ? Wp0 : (L == 1 ? Wp1 : Wp2)) + (16 * w + l15) * KD;
        #pragma unroll
        for (int s = 0; s < 6; ++s) {
            u16x8 b;
            #pragma unroll
            for (int j = 0; j < 8; ++j) {
                int k = 32 * s + 16 * (j >> 2) + 4 * l4 + (j & 3);
                b[j] = f2bf_u(Wrow[k]);
            }
            Bf[L][s] = __builtin_bit_cast(bf16x8, b);
        }
    }

    float sc[3], sh[3];
    if (PHASE == 2) {
        #pragma unroll
        for (int L = 0; L < 3; ++L) {
            int col = 64 * L + 16 * w + l15;
            sc[L] = stats[384 + col];
            sh[L] = stats[576 + col];
        }
    }

    float rSum[3] = {0.f, 0.f, 0.f}, rSq[3] = {0.f, 0.f, 0.f};
    float rS4 = 0.f, rQ4 = 0.f;

    for (int tile = blockIdx.x; tile < NTILES; tile += gridDim.x) {
        const int e0 = tile * TILE_M;
        __syncthreads();   // LDS reuse guard vs previous iteration
        // ---- stage Z tile as bf16
        #pragma unroll
        for (int i = 0; i < 18; ++i) {
            int q = i * 256 + t;          // 0..4607
            int row = q / 48;
            int col = (q - row * 48) * 4;
            int e = e0 + row;
            const float* src;
            if (col < 64) {
                int d = eidx[E_EDGES + e];           // edge_index[1] = dst
                src = x + (long)d * 64 + col;
            } else if (col < 128) {
                int nsrc = e / 12;                   // edge_index[0] = e/12 by construction
                src = x + (long)nsrc * 64 + (col - 64);
            } else {
                src = ea + (long)e * 64 + (col - 128);
            }
            f32x4 v = *(const f32x4*)src;
            u32x2 pk;
            pk[0] = (unsigned int)f2bf_u(v[0]) | ((unsigned int)f2bf_u(v[1]) << 16);
            pk[1] = (unsigned int)f2bf_u(v[2]) | ((unsigned int)f2bf_u(v[3]) << 16);
            *(u32x2*)(&zl[row * LDP + col]) = pk;
        }
        __syncthreads();

        // ---- MFMA: 6 row-tiles x 3 col-tiles (cols 16w+64L), K=192
        f32x4 acc[6][3];
        #pragma unroll
        for (int rt = 0; rt < 6; ++rt)
            #pragma unroll
            for (int L = 0; L < 3; ++L)
                acc[rt][L] = (f32x4){0.f, 0.f, 0.f, 0.f};

        #pragma unroll
        for (int s = 0; s < 6; ++s) {
            #pragma unroll
            for (int rt = 0; rt < 6; ++rt) {
                int row = rt * 16 + l15;
                int k0 = s * 32 + 4 * l4;
                u32x2 lo = *(const u32x2*)(&zl[row * LDP + k0]);
                u32x2 hi = *(const u32x2*)(&zl[row * LDP + k0 + 16]);
                u32x4 aw; aw[0] = lo[0]; aw[1] = lo[1]; aw[2] = hi[0]; aw[3] = hi[1];
                bf16x8 af = __builtin_bit_cast(bf16x8, aw);
                #pragma unroll
                for (int L = 0; L < 3; ++L)
                    acc[rt][L] = __builtin_amdgcn_mfma_f32_16x16x32_bf16(
                        af, Bf[L][s], acc[rt][L], 0, 0, 0);
            }
        }

        if (PHASE == 1) {
            #pragma unroll
            for (int L = 0; L < 3; ++L) {
                float s1 = 0.f, s2 = 0.f;
                #pragma unroll
                for (int rt = 0; rt < 6; ++rt)
                    #pragma unroll
                    for (int r = 0; r < 4; ++r) {
                        float v = acc[rt][L][r];
                        s1 += v; s2 += v * v;
                    }
                rSum[L] += s1; rSq[L] += s2;
            }
        } else {
            // bond output (no LDS involved)
            #pragma unroll
            for (int rt = 0; rt < 6; ++rt) {
                #pragma unroll
                for (int r = 0; r < 4; ++r) {
                    int e = e0 + rt * 16 + l4 * 4 + r;
                    int col = 16 * w + l15;
                    float bnd = acc[rt][2][r] * sc[2] + sh[2];
                    float eav = ea[(long)e * 64 + col];
                    outp[(long)N_NODES * 64 + (long)e * 64 + col] = splus(eav + bnd);
                }
            }
            __syncthreads();   // all waves done reading zl before overwrite
            // gated -> LDS
            #pragma unroll
            for (int rt = 0; rt < 6; ++rt) {
                #pragma unroll
                for (int r = 0; r < 4; ++r) {
                    int row = rt * 16 + l4 * 4 + r;
                    int col = 16 * w + l15;
                    float af_ = acc[rt][0][r] * sc[0] + sh[0];
                    float ac_ = acc[rt][1][r] * sc[1] + sh[1];
                    gl[row * 66 + col] = sigm(af_) * splus(ac_);
                }
            }
            __syncthreads();
            // segment-sum: 8 nodes x 64 cols, nodes fully inside tile
            #pragma unroll
            for (int p = 0; p < 2; ++p) {
                int pid = t + p * 256;       // 0..511
                int nl = pid >> 6;           // local node 0..7
                int col = pid & 63;          // == t & 63 for both p
                float s = 0.f;
                #pragma unroll
                for (int r = 0; r < 12; ++r)
                    s += gl[(nl * 12 + r) * 66 + col];
                int node = tile * 8 + nl;
                outp[(long)node * 64 + col] = s;   // raw nbr_sumed parked in out region
                rS4 += s; rQ4 += s * s;
            }
        }
    }

    if (PHASE == 1) {
        #pragma unroll
        for (int L = 0; L < 3; ++L) {
            float s1 = rSum[L], s2 = rSq[L];
            s1 += __shfl_xor(s1, 16); s1 += __shfl_xor(s1, 32);
            s2 += __shfl_xor(s2, 16); s2 += __shfl_xor(s2, 32);
            if (l4 == 0) {
                atomicAdd(&stats[64 * L + 16 * w + l15], s1);
                atomicAdd(&stats[192 + 64 * L + 16 * w + l15], s2);
            }
        }
    } else {
        __syncthreads();
        float* red = gl;                 // [2][4][64]
        red[w * 64 + (t & 63)] = rS4;
        red[256 + w * 64 + (t & 63)] = rQ4;
        __syncthreads();
        if (t < 64) {
            float a = red[t] + red[64 + t] + red[128 + t] + red[192 + t];
            float b = red[256 + t] + red[320 + t] + red[384 + t] + red[448 + t];
            atomicAdd(&stats[768 + t], a);
            atomicAdd(&stats[832 + t], b);
        }
    }
}

__global__ void finalize_k(const float* __restrict__ g1, const float* __restrict__ be1,
                           const float* __restrict__ g2, const float* __restrict__ be2,
                           const float* __restrict__ g3, const float* __restrict__ be3,
                           float* __restrict__ stats) {
    int j = threadIdx.x;
    if (j < 192) {
        float mean = stats[j] * (1.f / E_EDGES);
        float var  = stats[192 + j] * (1.f / E_EDGES) - mean * mean;
        float istd = rsqrtf(var + 1e-5f);
        int L = j >> 6, c = j & 63;
        const float* gp = (L == 0) ? g1 : ((L == 1) ? g2 : g3);
        const float* bp = (L == 0) ? be1 : ((L == 1) ? be2 : be3);
        float scv = gp[c] * istd;
        stats[384 + j] = scv;
        stats[576 + j] = bp[c] - mean * scv;
    }
}

__global__ void finalize4_k(const float* __restrict__ g4, const float* __restrict__ be4,
                            float* __restrict__ stats) {
    int j = threadIdx.x;
    if (j < 64) {
        float mean = stats[768 + j] * (1.f / N_NODES);
        float var  = stats[832 + j] * (1.f / N_NODES) - mean * mean;
        float istd = rsqrtf(var + 1e-5f);
        float scv = g4[j] * istd;
        stats[896 + j] = scv;
        stats[960 + j] = be4[j] - mean * scv;
    }
}

__global__ void out_k(const float* __restrict__ x, const float* __restrict__ stats,
                      float* __restrict__ outp) {
    long idx = (long)blockIdx.x * blockDim.x + threadIdx.x;   // vec4 index
    const long total = (long)N_NODES * 16;
    for (; idx < total; idx += (long)gridDim.x * blockDim.x) {
        int c4 = (int)(idx & 15) * 4;
        f32x4 sc = *(const f32x4*)(stats + 896 + c4);
        f32x4 sh = *(const f32x4*)(stats + 960 + c4);
        f32x4 nb = *(const f32x4*)(outp + idx * 4);
        f32x4 xv = *(const f32x4*)(x + idx * 4);
        f32x4 o;
        #pragma unroll
        for (int r = 0; r < 4; ++r) o[r] = splus(xv[r] + nb[r] * sc[r] + sh[r]);
        *(f32x4*)(outp + idx * 4) = o;
    }
}

extern "C" void kernel_launch(void* const* d_in, const int* in_sizes, int n_in,
                              void* d_out, int out_size, void* d_ws, size_t ws_size,
                              hipStream_t stream) {
    const float* x   = (const float*)d_in[0];
    const int*   ei  = (const int*)d_in[1];
    const float* ea  = (const float*)d_in[2];
    const float* Wc  = (const float*)d_in[3];
    const float* Wf  = (const float*)d_in[5];
    const float* Wb  = (const float*)d_in[7];
    const float* g1  = (const float*)d_in[9];   const float* be1 = (const float*)d_in[10];
    const float* g2  = (const float*)d_in[11];  const float* be2 = (const float*)d_in[12];
    const float* g3  = (const float*)d_in[13];  const float* be3 = (const float*)d_in[14];
    const float* g4  = (const float*)d_in[15];  const float* be4 = (const float*)d_in[16];
    float* stats = (float*)d_ws;
    float* outp  = (float*)d_out;

    hipMemsetAsync(d_ws, 0, 4096, stream);
    gemm_k<1><<<2048, 256, 0, stream>>>(x, ei, ea, Wc, Wf, Wb, stats, outp);
    finalize_k<<<1, 192, 0, stream>>>(g1, be1, g2, be2, g3, be3, stats);
    gemm_k<2><<<2048, 256, 0, stream>>>(x, ei, ea, Wc, Wf, Wb, stats, outp);
    finalize4_k<<<1, 64, 0, stream>>>(g4, be4, stats);
    out_k<<<2048, 256, 0, stream>>>(x, stats, outp);
}